// Round 7
// baseline (3501.202 us; speedup 1.0000x reference)
//
#include <hip/hip_runtime.h>

#define LL 8
#define DD 1024
#define VV 32000
#define SS 2048
#define BB 2
#define NROWS 4096          // B*S
#define DT_STEP 0.055f      // 0.5*(dt_min+dt_max)
#define HALF_DT 0.0275f
#define TUNNEL_SCALE 1.55f  // 1 + dt/dt_max

typedef __attribute__((ext_vector_type(8))) short bf16x8;
typedef __attribute__((ext_vector_type(4))) float f32x4;

static __device__ __forceinline__ float bf2f(unsigned short u){
  union { unsigned int i; float f; } v; v.i = ((unsigned int)u) << 16; return v.f;
}
static __device__ __forceinline__ unsigned short f2bf(float f){
  union { float f; unsigned int i; } v; v.f = f;
  unsigned int r = v.i + 0x7fffu + ((v.i >> 16) & 1u);
  return (unsigned short)(r >> 16);
}

// async global->LDS, 16B per lane. lds dest must be wave-uniform base; HW adds lane*16.
static __device__ __forceinline__ void gl16(const unsigned short* g, unsigned short* l){
  __builtin_amdgcn_global_load_lds(
      (const __attribute__((address_space(1))) unsigned int*)g,
      (__attribute__((address_space(3))) unsigned int*)l, 16, 0, 0);
}

__device__ __forceinline__ float block_sum256(float v, volatile float* scratch){
  #pragma unroll
  for (int off = 32; off; off >>= 1) v += __shfl_down(v, off, 64);
  int w = threadIdx.x >> 6, lane = threadIdx.x & 63;
  __syncthreads();
  if (lane == 0) scratch[w] = v;
  __syncthreads();
  return scratch[0] + scratch[1] + scratch[2] + scratch[3];
}

// ---------------- encode: phase embedding -> f32 master + bf16 hi/lo ----------------
__global__ void encode_kernel(const int* __restrict__ ids, float* __restrict__ s_f32,
                              unsigned short* __restrict__ hi, unsigned short* __restrict__ lo){
  int row = blockIdx.x;            // 0..4095 = b*S+s
  int t = threadIdx.x;
  float theta = 6.28318530717958647692f * (float)ids[row] / 32000.0f;
  #pragma unroll
  for (int i = 0; i < 2; ++i){
    int kk = t + i * 256;          // 0..511
    float ang = theta * (float)(kk + 1);
    float sv, cv; sincosf(ang, &sv, &cv);
    float c = cv * 0.03125f, s = sv * 0.03125f;   // 1/sqrt(D)
    long b0 = (long)row * DD + kk, b1 = b0 + 512;
    s_f32[b0] = c; s_f32[b1] = s;
    unsigned short ch = f2bf(c); hi[b0] = ch; lo[b0] = f2bf(c - bf2f(ch));
    unsigned short sh = f2bf(s); hi[b1] = sh; lo[b1] = f2bf(s - bf2f(sh));
  }
}

// ---------------- bf16 tiled transpose (hi+lo pair): [b][R][C] -> [b][C][R] ----------
__global__ void transpose_bf16_pair_kernel(const unsigned short* __restrict__ in_hi,
                                           const unsigned short* __restrict__ in_lo,
                                           unsigned short* __restrict__ out_hi,
                                           unsigned short* __restrict__ out_lo,
                                           int R, int C){
  __shared__ __align__(16) unsigned short tile[64][80];
  int zz = blockIdx.z;                       // (batch<<1) | sel
  const unsigned short* in = (zz & 1) ? in_lo : in_hi;
  unsigned short* out = (zz & 1) ? out_lo : out_hi;
  long ib = (long)(zz >> 1) * R * C;
  int c0 = blockIdx.x * 64, r0 = blockIdx.y * 64;
  int t = threadIdx.x;
  #pragma unroll
  for (int i = 0; i < 2; ++i){
    int j = t + i * 256; int row = j >> 3, cc = j & 7;
    *(uint4*)&tile[row][cc * 8] = *(const uint4*)(in + ib + (long)(r0 + row) * C + c0 + cc * 8);
  }
  __syncthreads();
  #pragma unroll
  for (int i = 0; i < 2; ++i){
    int j = t + i * 256; int orow = j >> 3, cc = j & 7;
    union { unsigned short u[8]; uint4 v; } tmp;
    #pragma unroll
    for (int e = 0; e < 8; ++e) tmp.u[e] = tile[cc * 8 + e][orow];
    *(uint4*)(out + ib + (long)(c0 + orow) * R + r0 + cc * 8) = tmp.v;
  }
}

// -------- f32 -> bf16 (optionally hi/lo split) transposing convert --------------------
template<bool SPLIT>
__global__ void transpose_f32_bf16_kernel(const float* __restrict__ in,
                                          unsigned short* __restrict__ ohi,
                                          unsigned short* __restrict__ olo, int R, int C){
  __shared__ float tile[64][68];
  long ib = (long)blockIdx.z * R * C;
  int c0 = blockIdx.x * 64, r0 = blockIdx.y * 64;
  int t = threadIdx.x;
  #pragma unroll
  for (int i = 0; i < 4; ++i){
    int j = t + i * 256; int row = j >> 4, cc = j & 15;
    *(float4*)&tile[row][cc * 4] = *(const float4*)(in + ib + (long)(r0 + row) * C + c0 + cc * 4);
  }
  __syncthreads();
  #pragma unroll
  for (int i = 0; i < 2; ++i){
    int j = t + i * 256; int orow = j >> 3, cc = j & 7;
    union { unsigned short u[8]; uint4 v; } th, tl;
    #pragma unroll
    for (int e = 0; e < 8; ++e){
      float v = tile[cc * 8 + e][orow];
      unsigned short h = f2bf(v); th.u[e] = h;
      if (SPLIT) tl.u[e] = f2bf(v - bf2f(h));
    }
    long ob = ib + (long)(c0 + orow) * R + r0 + cc * 8;
    *(uint4*)(ohi + ob) = th.v;
    if (SPLIT) *(uint4*)(olo + ob) = tl.v;
  }
}

// ---------------- split NT GEMM (128x128, 8 waves, ring-3): C = alpha * A @ B^T -------
// Operands as (hi,lo) bf16 pairs -> 3 MFMA products (fp32-class accuracy).
// LDS [3 ring][128 rows][64]: row = K-32 slab, chunks 0-3 hi / 4-7 lo, slot = chunk^(row&7)
// (row stride 128B -> bank = chunk*4+word, 8 chunks over 16 lanes = 2-way, free; r3: 0 conflicts).
// Ring-3 single-barrier schedule: {vmcnt(4) my-slice certified; barrier = cross-wave
// certify AND frees slot staged next; stage(t+2); compute(t)} -> ~2-tile load cover.
// OUTMODE: 0 = f32 C (+bias); 2 = bf16 hi/lo (score); 3 = f32 C + mid=S+dt*C hi/lo;
//          4 = C = S + 0.5dt*(K1+v)  (ev)
// CAUSAL: 0 none; 1 score-mode (skip upper tiles, mask diag); 2 pv-mode (k-limit)
template<int OUTMODE, int CAUSAL>
__global__ __launch_bounds__(512, 2)
void gemm_nt_kernel(const unsigned short* __restrict__ Ahi, const unsigned short* __restrict__ Alo,
                    const unsigned short* __restrict__ Bhi, const unsigned short* __restrict__ Blo,
                    float* __restrict__ C, unsigned short* __restrict__ Chi,
                    unsigned short* __restrict__ Clo, const float* __restrict__ bias,
                    const float* __restrict__ Sf, const float* __restrict__ K1f,
                    int K, int lda, int ldb, int ldc, int MT, int NT,
                    long batchA, long batchB, long batchC, float alpha)
{
  const int bz = blockIdx.y;
  const int nwg = MT * NT;
  const int q = nwg >> 3, r = nwg & 7;
  const int xcd = blockIdx.x & 7, off = blockIdx.x >> 3;
  const int wg = (xcd < r ? xcd * (q + 1) : r * (q + 1) + (xcd - r) * q) + off;
  const int band = wg / (NT << 3), rem = wg - band * (NT << 3);
  const int mt = (band << 3) + (rem & 7), nt = rem >> 3;
  if (CAUSAL == 1 && nt > mt) return;
  const int m0 = mt << 7, n0 = nt << 7;
  int Keff = K;
  if (CAUSAL == 2){ int kl = (mt + 1) << 7; Keff = kl < K ? kl : K; }

  __shared__ __align__(16) unsigned short sA[3][128][64];   // 48 KB
  __shared__ __align__(16) unsigned short sB[3][128][64];   // 48 KB

  const int tid = threadIdx.x;
  const int lane = tid & 63;
  const int w = tid >> 6;              // 0..7
  const int wr = w >> 2, wc = w & 3;   // 2 x 4 wave grid, 64x32 per wave
  const int fr = lane & 15, fc = lane >> 4;
  const int fr7 = fr & 7;

  f32x4 acc[4][2];
  #pragma unroll
  for (int i = 0; i < 4; ++i)
    #pragma unroll
    for (int j = 0; j < 2; ++j) acc[i][j] = (f32x4){0.f, 0.f, 0.f, 0.f};

  const int srow = tid >> 3, slot = tid & 7;
  const int cont = slot ^ (srow & 7);         // content chunk at this slot
  const long aoff = (long)bz * batchA, boff = (long)bz * batchB;
  const int gcol = (cont & 3) << 3;
  const unsigned short* gA = (cont >= 4 ? Alo : Ahi) + aoff + (long)(m0 + srow) * lda + gcol;
  const unsigned short* gB = (cont >= 4 ? Blo : Bhi) + boff + (long)(n0 + srow) * ldb + gcol;
  const long rstepA = 64L * lda, rstepB = 64L * ldb;
  const int wofs = w << 9;                    // wave base: w*8 rows * 64 elems

  #define STAGE(buf, kt) do {                                        \
    gl16(gA + (kt),          &sA[buf][0][0] + wofs);                 \
    gl16(gA + (kt) + rstepA, &sA[buf][0][0] + 4096 + wofs);          \
    gl16(gB + (kt),          &sB[buf][0][0] + wofs);                 \
    gl16(gB + (kt) + rstepB, &sB[buf][0][0] + 4096 + wofs);          \
  } while(0)

  const int oh = (fc ^ fr7) << 4;
  const int ol = ((4 + fc) ^ fr7) << 4;

  #define COMPUTE(buf) do {                                                         \
    const char* bA_ = (const char*)&sA[buf][0][0];                                  \
    const char* bB_ = (const char*)&sB[buf][0][0];                                  \
    bf16x8 ah_[4], al_[4];                                                          \
    _Pragma("unroll")                                                               \
    for (int mi = 0; mi < 4; ++mi){                                                 \
      const char* p_ = bA_ + (wr * 64 + mi * 16 + fr) * 128;                        \
      ah_[mi] = *(const bf16x8*)(p_ + oh);                                          \
      al_[mi] = *(const bf16x8*)(p_ + ol);                                          \
    }                                                                               \
    _Pragma("unroll")                                                               \
    for (int ni = 0; ni < 2; ++ni){                                                 \
      const char* pb_ = bB_ + (wc * 32 + ni * 16 + fr) * 128;                       \
      bf16x8 bh_ = *(const bf16x8*)(pb_ + oh);                                      \
      bf16x8 bl_ = *(const bf16x8*)(pb_ + ol);                                      \
      _Pragma("unroll")                                                             \
      for (int mi = 0; mi < 4; ++mi){                                               \
        acc[mi][ni] = __builtin_amdgcn_mfma_f32_16x16x32_bf16(ah_[mi], bh_, acc[mi][ni], 0, 0, 0);\
        acc[mi][ni] = __builtin_amdgcn_mfma_f32_16x16x32_bf16(ah_[mi], bl_, acc[mi][ni], 0, 0, 0);\
        acc[mi][ni] = __builtin_amdgcn_mfma_f32_16x16x32_bf16(al_[mi], bh_, acc[mi][ni], 0, 0, 0);\
      }                                                                             \
    }                                                                               \
  } while(0)

  const int ntiles = Keff >> 5;

  STAGE(0, 0);
  if (ntiles > 1) STAGE(1, 32);
  int cur = 0;
  for (int t = 0; t < ntiles; ++t){
    if (t < ntiles - 1) asm volatile("s_waitcnt vmcnt(4)" ::: "memory"); // my t-slice landed
    else               asm volatile("s_waitcnt vmcnt(0)" ::: "memory");
    asm volatile("s_barrier" ::: "memory");   // all certified; compute(t-1) done everywhere
    if (t + 2 < ntiles){
      int s2 = cur + 2; if (s2 >= 3) s2 -= 3;
      STAGE(s2, (t + 2) << 5);                // overlaps compute(t)
    }
    COMPUTE(cur);
    ++cur; if (cur == 3) cur = 0;
  }

  #undef STAGE
  #undef COMPUTE

  const long coff = (long)bz * batchC;
  const int rb0 = m0 + wr * 64 + fc * 4;   // + mi*16 + rg
  const int cb0 = n0 + wc * 32 + fr;       // + ni*16
  #pragma unroll
  for (int mi = 0; mi < 4; ++mi){
    #pragma unroll
    for (int ni = 0; ni < 2; ++ni){
      #pragma unroll
      for (int rg = 0; rg < 4; ++rg){
        int row = rb0 + mi * 16 + rg;
        int col = cb0 + ni * 16;
        float v = acc[mi][ni][rg] * alpha;
        long idx = coff + (long)row * ldc + col;
        if (OUTMODE == 0){
          if (bias) v += bias[col];
          C[idx] = v;
        } else if (OUTMODE == 2){
          if (CAUSAL == 1 && col > row) v = 0.0f;   // causal mask (k > q)
          unsigned short h = f2bf(v);
          Chi[idx] = h;
          Clo[idx] = f2bf(v - bf2f(h));
        } else if (OUTMODE == 3){                   // k1 + fused mid = s + dt*k1
          C[idx] = v;
          float m = Sf[idx] + DT_STEP * v;
          unsigned short h = f2bf(m);
          Chi[idx] = h;
          Clo[idx] = f2bf(m - bf2f(h));
        } else {                                    // fused ev = s + 0.5dt*(k1+k2)
          C[idx] = Sf[idx] + HALF_DT * (K1f[idx] + v);
        }
      }
    }
  }
}

// ---------------- 256x256 vocab GEMM, ring-4 deep pipeline: C = A @ B^T --------------
// BK=32, 4 LDS buffers (128 KB), 3-ahead prefetch, steady vmcnt(8), ONE barrier/tile.
// Swizzle fix (r6 had 4-way conflict): slot = chunk ^ SW(row), SW(r)=(r&3)^((r>>2)&1)
// -> start banks over 8 rows = {0,20,8,28,4,16,12,24}, 16 lanes -> 2-way = free.
// Epilogue: C store + fused per-row LSE partials, one slot per wave (nt*4+wc).
#define SW(r) ((((r) & 3)) ^ (((r) >> 2) & 1))
__global__ __launch_bounds__(512, 2)
void gemm256_kernel(const unsigned short* __restrict__ A,    // [4096][1024] bf16
                    const unsigned short* __restrict__ Bt,   // [32000][1024] bf16
                    float* __restrict__ C,                   // [4096][32000] f32
                    float* __restrict__ pmax,                // [4096][512] (500 used)
                    float* __restrict__ psum)                // [4096][512]
{
  const int MT = 16, NT = 125;
  const int nwg = MT * NT;
  const int q = nwg >> 3, r = nwg & 7;
  const int xcd = blockIdx.x & 7, off = blockIdx.x >> 3;
  const int wg = (xcd < r ? xcd * (q + 1) : r * (q + 1) + (xcd - r) * q) + off;
  const int band = wg / (NT << 3), rem = wg - band * (NT << 3);
  const int mt = (band << 3) + (rem & 7), nt = rem >> 3;
  const int m0 = mt << 8, n0 = nt << 8;

  __shared__ __align__(16) unsigned short sA[4][256][32];   // 64 KB
  __shared__ __align__(16) unsigned short sB[4][256][32];   // 64 KB

  const int tid = threadIdx.x;
  const int lane = tid & 63;
  const int w = tid >> 6;
  const int wr = w >> 2, wc = w & 3;     // 2 x 4, each wave 128x64 of C
  const int fr = lane & 15, fc = lane >> 4;

  f32x4 acc[8][4];
  #pragma unroll
  for (int i = 0; i < 8; ++i)
    #pragma unroll
    for (int j = 0; j < 4; ++j) acc[i][j] = (f32x4){0.f, 0.f, 0.f, 0.f};

  // staging: thread = (srow = tid>>2 in 0..127, slot = tid&3); 2 issues per operand
  const int srow = tid >> 2, slot = tid & 3;
  const int cont = slot ^ SW(srow);
  const unsigned short* gA = A  + (long)(m0 + srow) * DD + (cont << 3);
  const unsigned short* gB = Bt + (long)(n0 + srow) * DD + (cont << 3);
  const int wofs = w << 9;               // wave base: w*16 rows * 32 elems = 1 KB

  #define STG(buf, kt) do {                                                  \
    gl16(gA + (kt),                &sA[buf][0][0] + wofs);                   \
    gl16(gA + 128L * DD + (kt),    &sA[buf][0][0] + 4096 + wofs);            \
    gl16(gB + (kt),                &sB[buf][0][0] + wofs);                   \
    gl16(gB + 128L * DD + (kt),    &sB[buf][0][0] + 4096 + wofs);            \
  } while(0)

  STG(0, 0); STG(1, 32); STG(2, 64);     // 12 loads in flight per wave

  for (int t = 0; t < 32; ++t){
    // certify my tile-t slice: outstanding = slices of tiles (t+1, t+2) = 8
    if (t < 30)      asm volatile("s_waitcnt vmcnt(8)" ::: "memory");
    else if (t == 30) asm volatile("s_waitcnt vmcnt(4)" ::: "memory");
    else             asm volatile("s_waitcnt vmcnt(0)" ::: "memory");
    asm volatile("s_barrier" ::: "memory");  // all waves certified; compute(t-1) done
    if (t < 29) STG((t + 3) & 3, (t + 3) << 5);  // overlaps compute(t)

    const char* bA = (const char*)&sA[t & 3][0][0];
    const char* bB = (const char*)&sB[t & 3][0][0];
    bf16x8 aq[8], bq[4];
    #pragma unroll
    for (int mi = 0; mi < 8; ++mi){
      const int row = wr * 128 + mi * 16 + fr;
      aq[mi] = *(const bf16x8*)(bA + row * 64 + ((fc ^ SW(row)) << 4));
    }
    #pragma unroll
    for (int ni = 0; ni < 4; ++ni){
      const int row = wc * 64 + ni * 16 + fr;
      bq[ni] = *(const bf16x8*)(bB + row * 64 + ((fc ^ SW(row)) << 4));
    }
    __builtin_amdgcn_s_setprio(1);
    #pragma unroll
    for (int mi = 0; mi < 8; ++mi)
      #pragma unroll
      for (int ni = 0; ni < 4; ++ni)
        acc[mi][ni] = __builtin_amdgcn_mfma_f32_16x16x32_bf16(aq[mi], bq[ni], acc[mi][ni], 0, 0, 0);
    __builtin_amdgcn_s_setprio(0);
  }
  #undef STG

  const int rb0 = m0 + wr * 128 + fc * 4;
  const int cb0 = n0 + wc * 64 + fr;
  #pragma unroll
  for (int mi = 0; mi < 8; ++mi){
    #pragma unroll
    for (int ni = 0; ni < 4; ++ni){
      #pragma unroll
      for (int rg = 0; rg < 4; ++rg){
        C[(long)(rb0 + mi * 16 + rg) * VV + cb0 + ni * 16] = acc[mi][ni][rg];
      }
    }
  }

  // fused LSE partials: per row, this WAVE's 64 cols; 16-lane (fr) shfl reduce
  #pragma unroll
  for (int mi = 0; mi < 8; ++mi){
    #pragma unroll
    for (int rg = 0; rg < 4; ++rg){
      float m4 = fmaxf(fmaxf(acc[mi][0][rg], acc[mi][1][rg]),
                       fmaxf(acc[mi][2][rg], acc[mi][3][rg]));
      #pragma unroll
      for (int o = 1; o < 16; o <<= 1) m4 = fmaxf(m4, __shfl_xor(m4, o, 64));
      float s4 = __expf(acc[mi][0][rg] - m4) + __expf(acc[mi][1][rg] - m4)
               + __expf(acc[mi][2][rg] - m4) + __expf(acc[mi][3][rg] - m4);
      #pragma unroll
      for (int o = 1; o < 16; o <<= 1) s4 += __shfl_xor(s4, o, 64);
      if (fr == 0){
        long pidx = ((long)(rb0 + mi * 16 + rg) << 9) + nt * 4 + wc;  // per-wave slot
        pmax[pidx] = m4;
        psum[pidx] = s4;
      }
    }
  }
}
#undef SW

// ---------------- elementwise / reduction kernels ------------------------------------
__global__ void energy_kernel(const float* __restrict__ ev, float* __restrict__ energy){
  int row = blockIdx.x, t = threadIdx.x;
  long base = (long)row * DD + t * 4;
  float4 v = *(const float4*)(ev + base);
  __shared__ float scratch[4];
  float n2 = block_sum256(v.x*v.x + v.y*v.y + v.z*v.z + v.w*v.w, scratch);
  if (t == 0) energy[row] = sqrtf(n2);
}

__global__ void mean_energy_kernel(const float* __restrict__ energy, float* __restrict__ thr){
  int b = blockIdx.x, t = threadIdx.x;
  float s = 0.f;
  for (int j = t; j < SS; j += 256) s += energy[b * SS + j];
  __shared__ float scratch[4];
  float tot = block_sum256(s, scratch);
  if (t == 0) thr[b] = tot * (1.0f / SS);
}

__global__ void tunnel_kernel(const float* __restrict__ ev, const float* __restrict__ energy,
                              const float* __restrict__ thr,
                              unsigned short* __restrict__ hi, unsigned short* __restrict__ lo){
  int row = blockIdx.x, t = threadIdx.x;
  float scale = (energy[row] < thr[row >> 11]) ? TUNNEL_SCALE : 1.0f;
  long base = (long)row * DD + t * 4;
  float4 v = *(const float4*)(ev + base);
  v.x *= scale; v.y *= scale; v.z *= scale; v.w *= scale;
  ushort4 hv, lv;
  hv.x = f2bf(v.x); lv.x = f2bf(v.x - bf2f(hv.x));
  hv.y = f2bf(v.y); lv.y = f2bf(v.y - bf2f(hv.y));
  hv.z = f2bf(v.z); lv.z = f2bf(v.z - bf2f(hv.z));
  hv.w = f2bf(v.w); lv.w = f2bf(v.w - bf2f(hv.w));
  *(ushort4*)(hi + base) = hv; *(ushort4*)(lo + base) = lv;
}

__global__ void ln_kernel(const float* __restrict__ h, const float* __restrict__ w,
                          const float* __restrict__ b, float* __restrict__ s_f32,
                          unsigned short* __restrict__ hi, unsigned short* __restrict__ lo){
  int row = blockIdx.x, t = threadIdx.x;
  long base = (long)row * DD + t * 4;
  float4 xv = *(const float4*)(h + base);
  __shared__ float scratch[4];
  float sum = block_sum256(xv.x + xv.y + xv.z + xv.w, scratch);
  float ssq = block_sum256(xv.x*xv.x + xv.y*xv.y + xv.z*xv.z + xv.w*xv.w, scratch);
  float mu = sum * (1.0f / DD);
  float var = ssq * (1.0f / DD) - mu * mu;
  float rstd = rsqrtf(var + 1e-5f);
  float4 wv = *(const float4*)(w + t * 4), bv = *(const float4*)(b + t * 4);
  float y0 = (xv.x - mu) * rstd * wv.x + bv.x;
  float y1 = (xv.y - mu) * rstd * wv.y + bv.y;
  float y2 = (xv.z - mu) * rstd * wv.z + bv.z;
  float y3 = (xv.w - mu) * rstd * wv.w + bv.w;
  float4 o; o.x = y0; o.y = y1; o.z = y2; o.w = y3;
  *(float4*)(s_f32 + base) = o;
  ushort4 hv, lv;
  hv.x = f2bf(y0); lv.x = f2bf(y0 - bf2f(hv.x));
  hv.y = f2bf(y1); lv.y = f2bf(y1 - bf2f(hv.y));
  hv.z = f2bf(y2); lv.z = f2bf(y2 - bf2f(hv.z));
  hv.w = f2bf(y3); lv.w = f2bf(y3 - bf2f(hv.w));
  *(ushort4*)(hi + base) = hv; *(ushort4*)(lo + base) = lv;
}

// final LN + unit-normalize -> bf16 (plain; un-amplified error)
__global__ void fln_kernel(const float* __restrict__ s, const float* __restrict__ w,
                           const float* __restrict__ b, unsigned short* __restrict__ uhi){
  int row = blockIdx.x, t = threadIdx.x;
  long base = (long)row * DD + t * 4;
  float4 xv = *(const float4*)(s + base);
  __shared__ float scratch[4];
  float sum = block_sum256(xv.x + xv.y + xv.z + xv.w, scratch);
  float ssq = block_sum256(xv.x*xv.x + xv.y*xv.y + xv.z*xv.z + xv.w*xv.w, scratch);
  float mu = sum * (1.0f / DD);
  float var = ssq * (1.0f / DD) - mu * mu;
  float rstd = rsqrtf(var + 1e-5f);
  float4 wv = *(const float4*)(w + t * 4), bv = *(const float4*)(b + t * 4);
  float y0 = (xv.x - mu) * rstd * wv.x + bv.x;
  float y1 = (xv.y - mu) * rstd * wv.y + bv.y;
  float y2 = (xv.z - mu) * rstd * wv.z + bv.z;
  float y3 = (xv.w - mu) * rstd * wv.w + bv.w;
  float n2 = block_sum256(y0*y0 + y1*y1 + y2*y2 + y3*y3, scratch);
  float inv = 1.0f / (sqrtf(n2) + 1e-12f);
  ushort4 o;
  o.x = f2bf(y0 * inv); o.y = f2bf(y1 * inv);
  o.z = f2bf(y2 * inv); o.w = f2bf(y3 * inv);
  *(ushort4*)(uhi + base) = o;
}

// ---------------- loss: combine per-wave LSE partials (500 per row) ------------------
__global__ void lse_reduce_kernel(const float* __restrict__ pmax, const float* __restrict__ psum,
                                  const float* __restrict__ logits, const int* __restrict__ labels,
                                  float* __restrict__ lrow){
  int idx = blockIdx.x;               // 0..4093
  int b = idx / (SS - 1), qq = idx - b * (SS - 1);
  int row = b * SS + qq;
  int t = threadIdx.x;                // 64 threads
  float m = -1e30f, l = 0.f;
  for (int p = t; p < 500; p += 64){
    float pm = pmax[((long)row << 9) + p], pl = psum[((long)row << 9) + p];
    float M = fmaxf(m, pm);
    l = l * __expf(m - M) + pl * __expf(pm - M);
    m = M;
  }
  #pragma unroll
  for (int o = 1; o < 64; o <<= 1){
    float m2 = __shfl_xor(m, o, 64), l2 = __shfl_xor(l, o, 64);
    float M = fmaxf(m, m2);
    l = l * __expf(m - M) + l2 * __expf(m2 - M);
    m = M;
  }
  if (t == 0){
    float lse = m + __logf(l);
    float tl = logits[(long)row * VV + labels[row + 1]];
    lrow[idx] = lse - tl;
  }
}

__global__ void loss_reduce_kernel(const float* __restrict__ lrow, float* __restrict__ dst){
  __shared__ float scratch[4];
  float s = 0.f;
  for (int j = threadIdx.x; j < BB * (SS - 1); j += 256) s += lrow[j];
  float tot = block_sum256(s, scratch);
  if (threadIdx.x == 0) dst[0] = tot / (float)(BB * (SS - 1));
}

// ---------------- launch ------------------------------------------------------------
extern "C" void kernel_launch(void* const* d_in, const int* in_sizes, int n_in,
                              void* d_out, int out_size, void* d_ws, size_t ws_size,
                              hipStream_t stream) {
  const int*   ids    = (const int*)d_in[0];
  const int*   labels = (const int*)d_in[1];
  const float* proj_w = (const float*)d_in[2];
  const float* proj_b = (const float*)d_in[3];
  const float* ln_w   = (const float*)d_in[4];
  const float* ln_b   = (const float*)d_in[5];
  const float* fln_w  = (const float*)d_in[6];
  const float* fln_b  = (const float*)d_in[7];
  const float* out_w  = (const float*)d_in[8];
  float* out = (float*)d_out;

  char* ws = (char*)d_ws;
  float*          s_f32 = (float*)(ws + 0);                    // 16.78 MB
  unsigned short* op_hi = (unsigned short*)(ws + 16777216);    //  8.39 MB (states/mid/ev/u hi)
  unsigned short* op_lo = (unsigned short*)(ws + 25165824);    //  8.39 MB
  unsigned short* T_hi  = (unsigned short*)(ws + 33554432);    //  8.39 MB (transposed operand)
  unsigned short* T_lo  = (unsigned short*)(ws + 41943040);    //  8.39 MB
  float*          k1    = (float*)(ws + 50331648);             // 16.78 MB (also h pre-LN)
  float*          k2    = (float*)(ws + 67108864);             // 16.78 MB (ev)
  unsigned short* sc_hi = (unsigned short*)(ws + 83886080);    //  8.39 MB (score hi)
  unsigned short* sc_lo = (unsigned short*)(ws + 92274688);    //  8.39 MB
  unsigned short* WhiT  = (unsigned short*)(ws + 100663296);   // 16.78 MB [L][n][k]
  unsigned short* WloT  = (unsigned short*)(ws + 117440512);   // 16.78 MB
  float*          energy= (float*)(ws + 134217728);
  float*          thr   = (float*)(ws + 134234112);
  float*          lrow  = (float*)(ws + 134234368);
  unsigned short* owT   = T_hi;  // 65.54 MB, overlays T/k/score zone (dead at vocab time)
  float*          pmax  = (float*)(ws + 0);          // overlays s_f32 (dead after fln), 8 MB
  float*          psum  = (float*)(ws + 8388608);    // 8 MB

  // proj_w [L][k][n] -> WhiT/WloT [L][n][k] (fp32-split bf16)
  transpose_f32_bf16_kernel<true><<<dim3(16, 16, 8), 256, 0, stream>>>(proj_w, WhiT, WloT, DD, DD);
  // encode
  encode_kernel<<<NROWS, 256, 0, stream>>>(ids, s_f32, op_hi, op_lo);
  transpose_bf16_pair_kernel<<<dim3(16, 32, 4), 256, 0, stream>>>(op_hi, op_lo, T_hi, T_lo, SS, DD);

  for (int l = 0; l < LL; ++l){
    // score1 = tril(states @ statesT)/32  -> bf16 hi/lo
    gemm_nt_kernel<2, 1><<<dim3(256, 2), 512, 0, stream>>>(
        op_hi, op_lo, op_hi, op_lo, nullptr, sc_hi, sc_lo, nullptr, nullptr, nullptr,
        DD, DD, DD, SS, 16, 16, (long)SS * DD, (long)SS * DD, (long)SS * SS, 0.03125f);
    // k1 = score1 @ states ; fused: mid = states + dt*k1 -> op hi/lo
    gemm_nt_kernel<3, 2><<<dim3(128, 2), 512, 0, stream>>>(
        sc_hi, sc_lo, T_hi, T_lo, k1, op_hi, op_lo, nullptr, s_f32, nullptr,
        SS, SS, SS, DD, 16, 8, (long)SS * SS, (long)DD * SS, (long)SS * DD, 1.0f);
    transpose_bf16_pair_kernel<<<dim3(16, 32, 4), 256, 0, stream>>>(op_hi, op_lo, T_hi, T_lo, SS, DD);
    // score2 = tril(mid @ midT)/32
    gemm_nt_kernel<2, 1><<<dim3(256, 2), 512, 0, stream>>>(
        op_hi, op_lo, op_hi, op_lo, nullptr, sc_hi, sc_lo, nullptr, nullptr, nullptr,
        DD, DD, DD, SS, 16, 16, (long)SS * DD, (long)SS * DD, (long)SS * SS, 0.03125f);
    // k2 = score2 @ mid ; fused: ev = states + 0.5dt*(k1+k2)  (written to k2 buffer)
    gemm_nt_kernel<4, 2><<<dim3(128, 2), 512, 0, stream>>>(
        sc_hi, sc_lo, T_hi, T_lo, k2, nullptr, nullptr, nullptr, s_f32, k1,
        SS, SS, SS, DD, 16, 8, (long)SS * SS, (long)DD * SS, (long)SS * DD, 1.0f);
    // row energies + threshold + tunneling
    energy_kernel<<<NROWS, 256, 0, stream>>>(k2, energy);
    mean_energy_kernel<<<BB, 256, 0, stream>>>(energy, thr);
    tunnel_kernel<<<NROWS, 256, 0, stream>>>(k2, energy, thr, op_hi, op_lo);
    // h = ev @ proj_w[l] + proj_b[l]  (into k1)
    gemm_nt_kernel<0, 0><<<dim3(256, 1), 512, 0, stream>>>(
        op_hi, op_lo, WhiT + (long)l * DD * DD, WloT + (long)l * DD * DD,
        k1, nullptr, nullptr, proj_b + l * DD, nullptr, nullptr,
        DD, DD, DD, DD, 32, 8, 0, 0, 0, 1.0f);
    // states = LN(h)
    ln_kernel<<<NROWS, 256, 0, stream>>>(k1, ln_w + l * DD, ln_b + l * DD, s_f32, op_hi, op_lo);
    if (l < LL - 1){
      transpose_bf16_pair_kernel<<<dim3(16, 32, 4), 256, 0, stream>>>(op_hi, op_lo, T_hi, T_lo, SS, DD);
    }
  }

  // out_w [k][v] -> owT [v][k] bf16 (plain); u = unit(LN(states)) -> op_hi
  transpose_f32_bf16_kernel<false><<<dim3(500, 16, 1), 256, 0, stream>>>(out_w, owT, nullptr, DD, VV);
  fln_kernel<<<NROWS, 256, 0, stream>>>(s_f32, fln_w, fln_b, op_hi);
  // logits = u @ out_w  (ring-4 pipelined 256^2) + fused per-wave LSE partials
  gemm256_kernel<<<2000, 512, 0, stream>>>(op_hi, owT, out, pmax, psum);
  // loss from partials
  lse_reduce_kernel<<<BB * (SS - 1), 64, 0, stream>>>(pmax, psum, out, labels, lrow);
  loss_reduce_kernel<<<1, 256, 0, stream>>>(lrow, out + (long)NROWS * VV);
}

// Round 8
// 2975.434 us; speedup vs baseline: 1.1767x; 1.1767x over previous
//
#include <hip/hip_runtime.h>

#define LL 8
#define DD 1024
#define VV 32000
#define SS 2048
#define BB 2
#define NROWS 4096          // B*S
#define DT_STEP 0.055f      // 0.5*(dt_min+dt_max)
#define HALF_DT 0.0275f
#define TUNNEL_SCALE 1.55f  // 1 + dt/dt_max

typedef __attribute__((ext_vector_type(8))) short bf16x8;
typedef __attribute__((ext_vector_type(4))) float f32x4;

static __device__ __forceinline__ float bf2f(unsigned short u){
  union { unsigned int i; float f; } v; v.i = ((unsigned int)u) << 16; return v.f;
}
static __device__ __forceinline__ unsigned short f2bf(float f){
  union { float f; unsigned int i; } v; v.f = f;
  unsigned int r = v.i + 0x7fffu + ((v.i >> 16) & 1u);
  return (unsigned short)(r >> 16);
}

// async global->LDS, 16B per lane. lds dest must be wave-uniform base; HW adds lane*16.
static __device__ __forceinline__ void gl16(const unsigned short* g, unsigned short* l){
  __builtin_amdgcn_global_load_lds(
      (const __attribute__((address_space(1))) unsigned int*)g,
      (__attribute__((address_space(3))) unsigned int*)l, 16, 0, 0);
}

__device__ __forceinline__ float block_sum256(float v, volatile float* scratch){
  #pragma unroll
  for (int off = 32; off; off >>= 1) v += __shfl_down(v, off, 64);
  int w = threadIdx.x >> 6, lane = threadIdx.x & 63;
  __syncthreads();
  if (lane == 0) scratch[w] = v;
  __syncthreads();
  return scratch[0] + scratch[1] + scratch[2] + scratch[3];
}

// ---------------- encode: phase embedding -> f32 master + bf16 hi/lo ----------------
__global__ void encode_kernel(const int* __restrict__ ids, float* __restrict__ s_f32,
                              unsigned short* __restrict__ hi, unsigned short* __restrict__ lo){
  int row = blockIdx.x;            // 0..4095 = b*S+s
  int t = threadIdx.x;
  float theta = 6.28318530717958647692f * (float)ids[row] / 32000.0f;
  #pragma unroll
  for (int i = 0; i < 2; ++i){
    int kk = t + i * 256;          // 0..511
    float ang = theta * (float)(kk + 1);
    float sv, cv; sincosf(ang, &sv, &cv);
    float c = cv * 0.03125f, s = sv * 0.03125f;   // 1/sqrt(D)
    long b0 = (long)row * DD + kk, b1 = b0 + 512;
    s_f32[b0] = c; s_f32[b1] = s;
    unsigned short ch = f2bf(c); hi[b0] = ch; lo[b0] = f2bf(c - bf2f(ch));
    unsigned short sh = f2bf(s); hi[b1] = sh; lo[b1] = f2bf(s - bf2f(sh));
  }
}

// ---------------- bf16 tiled transpose (hi+lo pair): [b][R][C] -> [b][C][R] ----------
__global__ void transpose_bf16_pair_kernel(const unsigned short* __restrict__ in_hi,
                                           const unsigned short* __restrict__ in_lo,
                                           unsigned short* __restrict__ out_hi,
                                           unsigned short* __restrict__ out_lo,
                                           int R, int C){
  __shared__ __align__(16) unsigned short tile[64][80];
  int zz = blockIdx.z;                       // (batch<<1) | sel
  const unsigned short* in = (zz & 1) ? in_lo : in_hi;
  unsigned short* out = (zz & 1) ? out_lo : out_hi;
  long ib = (long)(zz >> 1) * R * C;
  int c0 = blockIdx.x * 64, r0 = blockIdx.y * 64;
  int t = threadIdx.x;
  #pragma unroll
  for (int i = 0; i < 2; ++i){
    int j = t + i * 256; int row = j >> 3, cc = j & 7;
    *(uint4*)&tile[row][cc * 8] = *(const uint4*)(in + ib + (long)(r0 + row) * C + c0 + cc * 8);
  }
  __syncthreads();
  #pragma unroll
  for (int i = 0; i < 2; ++i){
    int j = t + i * 256; int orow = j >> 3, cc = j & 7;
    union { unsigned short u[8]; uint4 v; } tmp;
    #pragma unroll
    for (int e = 0; e < 8; ++e) tmp.u[e] = tile[cc * 8 + e][orow];
    *(uint4*)(out + ib + (long)(c0 + orow) * R + r0 + cc * 8) = tmp.v;
  }
}

// -------- f32 -> bf16 (optionally hi/lo split) transposing convert --------------------
template<bool SPLIT>
__global__ void transpose_f32_bf16_kernel(const float* __restrict__ in,
                                          unsigned short* __restrict__ ohi,
                                          unsigned short* __restrict__ olo, int R, int C){
  __shared__ float tile[64][68];
  long ib = (long)blockIdx.z * R * C;
  int c0 = blockIdx.x * 64, r0 = blockIdx.y * 64;
  int t = threadIdx.x;
  #pragma unroll
  for (int i = 0; i < 4; ++i){
    int j = t + i * 256; int row = j >> 4, cc = j & 15;
    *(float4*)&tile[row][cc * 4] = *(const float4*)(in + ib + (long)(r0 + row) * C + c0 + cc * 4);
  }
  __syncthreads();
  #pragma unroll
  for (int i = 0; i < 2; ++i){
    int j = t + i * 256; int orow = j >> 3, cc = j & 7;
    union { unsigned short u[8]; uint4 v; } th, tl;
    #pragma unroll
    for (int e = 0; e < 8; ++e){
      float v = tile[cc * 8 + e][orow];
      unsigned short h = f2bf(v); th.u[e] = h;
      if (SPLIT) tl.u[e] = f2bf(v - bf2f(h));
    }
    long ob = ib + (long)(c0 + orow) * R + r0 + cc * 8;
    *(uint4*)(ohi + ob) = th.v;
    if (SPLIT) *(uint4*)(olo + ob) = tl.v;
  }
}

// ---------------- split NT GEMM (128x128, 8 waves, dbuf): C = alpha * A @ B^T ---------
// Reverted to the r6-proven dbuf-2 structure (64 KB LDS -> 2 blocks/CU TLP).
// Operands as (hi,lo) bf16 pairs -> 3 MFMA products (fp32-class accuracy).
// LDS [2 dbuf][128 rows][64]: row = K-32 slab, chunks 0-3 hi / 4-7 lo, slot = chunk^(row&7).
// OUTMODE: 0 = f32 C (+bias); 2 = bf16 hi/lo (score); 3 = f32 C + mid=S+dt*C hi/lo;
//          4 = C = S + 0.5dt*(K1+v)  (ev)
// CAUSAL: 0 none; 1 score-mode (skip upper tiles, mask diag); 2 pv-mode (k-limit)
template<int OUTMODE, int CAUSAL>
__global__ __launch_bounds__(512, 4)
void gemm_nt_kernel(const unsigned short* __restrict__ Ahi, const unsigned short* __restrict__ Alo,
                    const unsigned short* __restrict__ Bhi, const unsigned short* __restrict__ Blo,
                    float* __restrict__ C, unsigned short* __restrict__ Chi,
                    unsigned short* __restrict__ Clo, const float* __restrict__ bias,
                    const float* __restrict__ Sf, const float* __restrict__ K1f,
                    int K, int lda, int ldb, int ldc, int MT, int NT,
                    long batchA, long batchB, long batchC, float alpha)
{
  const int bz = blockIdx.y;
  const int nwg = MT * NT;
  const int q = nwg >> 3, r = nwg & 7;
  const int xcd = blockIdx.x & 7, off = blockIdx.x >> 3;
  const int wg = (xcd < r ? xcd * (q + 1) : r * (q + 1) + (xcd - r) * q) + off;
  const int band = wg / (NT << 3), rem = wg - band * (NT << 3);
  const int mt = (band << 3) + (rem & 7), nt = rem >> 3;
  if (CAUSAL == 1 && nt > mt) return;
  const int m0 = mt << 7, n0 = nt << 7;
  int Keff = K;
  if (CAUSAL == 2){ int kl = (mt + 1) << 7; Keff = kl < K ? kl : K; }

  __shared__ __align__(16) unsigned short sA[2][128][64];
  __shared__ __align__(16) unsigned short sB[2][128][64];

  const int tid = threadIdx.x;
  const int lane = tid & 63;
  const int w = tid >> 6;              // 0..7
  const int wr = w >> 2, wc = w & 3;   // 2 x 4 wave grid, 64x32 per wave
  const int fr = lane & 15, fc = lane >> 4;
  const int fr7 = fr & 7;

  f32x4 acc[4][2];
  #pragma unroll
  for (int i = 0; i < 4; ++i)
    #pragma unroll
    for (int j = 0; j < 2; ++j) acc[i][j] = (f32x4){0.f, 0.f, 0.f, 0.f};

  const int srow = tid >> 3, slot = tid & 7;
  const int cont = slot ^ (srow & 7);         // content chunk at this slot
  const long aoff = (long)bz * batchA, boff = (long)bz * batchB;
  const int gcol = (cont & 3) << 3;
  const unsigned short* gA = (cont >= 4 ? Alo : Ahi) + aoff + (long)(m0 + srow) * lda + gcol;
  const unsigned short* gB = (cont >= 4 ? Blo : Bhi) + boff + (long)(n0 + srow) * ldb + gcol;
  const long rstepA = 64L * lda, rstepB = 64L * ldb;
  const int wofs = w << 9;                    // wave base: w*8 rows * 64 elems

  #define STAGE(buf, kt) do {                                        \
    gl16(gA + (kt),          &sA[buf][0][0] + wofs);                 \
    gl16(gA + (kt) + rstepA, &sA[buf][0][0] + 4096 + wofs);          \
    gl16(gB + (kt),          &sB[buf][0][0] + wofs);                 \
    gl16(gB + (kt) + rstepB, &sB[buf][0][0] + 4096 + wofs);          \
  } while(0)

  const int oh = (fc ^ fr7) << 4;
  const int ol = ((4 + fc) ^ fr7) << 4;

  #define COMPUTE(buf) do {                                                         \
    const char* bA_ = (const char*)&sA[buf][0][0];                                  \
    const char* bB_ = (const char*)&sB[buf][0][0];                                  \
    bf16x8 ah_[4], al_[4];                                                          \
    _Pragma("unroll")                                                               \
    for (int mi = 0; mi < 4; ++mi){                                                 \
      const char* p_ = bA_ + (wr * 64 + mi * 16 + fr) * 128;                        \
      ah_[mi] = *(const bf16x8*)(p_ + oh);                                          \
      al_[mi] = *(const bf16x8*)(p_ + ol);                                          \
    }                                                                               \
    _Pragma("unroll")                                                               \
    for (int ni = 0; ni < 2; ++ni){                                                 \
      const char* pb_ = bB_ + (wc * 32 + ni * 16 + fr) * 128;                       \
      bf16x8 bh_ = *(const bf16x8*)(pb_ + oh);                                      \
      bf16x8 bl_ = *(const bf16x8*)(pb_ + ol);                                      \
      _Pragma("unroll")                                                             \
      for (int mi = 0; mi < 4; ++mi){                                               \
        acc[mi][ni] = __builtin_amdgcn_mfma_f32_16x16x32_bf16(ah_[mi], bh_, acc[mi][ni], 0, 0, 0);\
        acc[mi][ni] = __builtin_amdgcn_mfma_f32_16x16x32_bf16(ah_[mi], bl_, acc[mi][ni], 0, 0, 0);\
        acc[mi][ni] = __builtin_amdgcn_mfma_f32_16x16x32_bf16(al_[mi], bh_, acc[mi][ni], 0, 0, 0);\
      }                                                                             \
    }                                                                               \
  } while(0)

  const int ntiles = Keff >> 5;

  STAGE(0, 0);
  int cur = 0;
  for (int t = 0; t < ntiles - 1; ++t){
    asm volatile("s_barrier" ::: "memory");           // prev compute on cur^1 done
    STAGE(cur ^ 1, (t + 1) << 5);                     // issue next tile (4 loads fly)
    asm volatile("s_waitcnt vmcnt(4)" ::: "memory");  // my tile-t loads landed
    asm volatile("s_barrier" ::: "memory");           // everyone's landed
    COMPUTE(cur);
    cur ^= 1;
  }
  asm volatile("s_waitcnt vmcnt(0)" ::: "memory");
  asm volatile("s_barrier" ::: "memory");
  COMPUTE(cur);

  #undef STAGE
  #undef COMPUTE

  const long coff = (long)bz * batchC;
  const int rb0 = m0 + wr * 64 + fc * 4;   // + mi*16 + rg
  const int cb0 = n0 + wc * 32 + fr;       // + ni*16
  #pragma unroll
  for (int mi = 0; mi < 4; ++mi){
    #pragma unroll
    for (int ni = 0; ni < 2; ++ni){
      #pragma unroll
      for (int rg = 0; rg < 4; ++rg){
        int row = rb0 + mi * 16 + rg;
        int col = cb0 + ni * 16;
        float v = acc[mi][ni][rg] * alpha;
        long idx = coff + (long)row * ldc + col;
        if (OUTMODE == 0){
          if (bias) v += bias[col];
          C[idx] = v;
        } else if (OUTMODE == 2){
          if (CAUSAL == 1 && col > row) v = 0.0f;   // causal mask (k > q)
          unsigned short h = f2bf(v);
          Chi[idx] = h;
          Clo[idx] = f2bf(v - bf2f(h));
        } else if (OUTMODE == 3){                   // k1 + fused mid = s + dt*k1
          C[idx] = v;
          float m = Sf[idx] + DT_STEP * v;
          unsigned short h = f2bf(m);
          Chi[idx] = h;
          Clo[idx] = f2bf(m - bf2f(h));
        } else {                                    // fused ev = s + 0.5dt*(k1+k2)
          C[idx] = Sf[idx] + HALF_DT * (K1f[idx] + v);
        }
      }
    }
  }
}

// ---------------- 256x256 vocab GEMM v3: r4 layout + stage-all-early ------------------
// BK=64, LDS [2][256][64] per operand (128 KB; r4-measured 0 bank conflicts).
// Per tile: {barrier (buffer free) -> stage ALL 8 slices of t+1 -> vmcnt(8) certify
// tile t (cover = full previous compute) -> barrier -> 24 ds_read + 64 MFMA, no
// internal barriers}. Fixes r4's 1-phase cover on its youngest loads.
// Epilogue: C store + fused per-row LSE partials, one slot per wave (nt*4+wc).
__global__ __launch_bounds__(512, 2)
void gemm256_kernel(const unsigned short* __restrict__ A,    // [4096][1024] bf16
                    const unsigned short* __restrict__ Bt,   // [32000][1024] bf16
                    float* __restrict__ C,                   // [4096][32000] f32
                    float* __restrict__ pmax,                // [4096][512] (500 used)
                    float* __restrict__ psum)                // [4096][512]
{
  const int MT = 16, NT = 125;
  const int nwg = MT * NT;
  const int q = nwg >> 3, r = nwg & 7;
  const int xcd = blockIdx.x & 7, off = blockIdx.x >> 3;
  const int wg = (xcd < r ? xcd * (q + 1) : r * (q + 1) + (xcd - r) * q) + off;
  const int band = wg / (NT << 3), rem = wg - band * (NT << 3);
  const int mt = (band << 3) + (rem & 7), nt = rem >> 3;
  const int m0 = mt << 8, n0 = nt << 8;

  __shared__ __align__(16) unsigned short sA[2][256][64];   // 64 KB
  __shared__ __align__(16) unsigned short sB[2][256][64];   // 64 KB

  const int tid = threadIdx.x;
  const int lane = tid & 63;
  const int w = tid >> 6;
  const int wr = w >> 2, wc = w & 3;     // 2 x 4, each wave 128x64 of C
  const int fr = lane & 15, fc = lane >> 4;
  const int fr7 = fr & 7;

  f32x4 acc[8][4];
  #pragma unroll
  for (int i = 0; i < 8; ++i)
    #pragma unroll
    for (int j = 0; j < 4; ++j) acc[i][j] = (f32x4){0.f, 0.f, 0.f, 0.f};

  // staging: thread = (srow = tid>>3 in 0..63, slot = tid&7); 4 issues per operand
  const int srow = tid >> 3, slot = tid & 7;
  const int cont = slot ^ (srow & 7);
  const unsigned short* gA = A  + (long)(m0 + srow) * DD + (cont << 3);
  const unsigned short* gB = Bt + (long)(n0 + srow) * DD + (cont << 3);
  const int wofs = w << 9;               // wave base: w*8 rows * 64 elems = 1 KB

  #define STG(buf, kt) do {                                                        \
    _Pragma("unroll")                                                              \
    for (int i_ = 0; i_ < 4; ++i_){                                                \
      gl16(gA + (long)(i_ * 64) * DD + (kt), &sA[buf][0][0] + i_ * 4096 + wofs);   \
      gl16(gB + (long)(i_ * 64) * DD + (kt), &sB[buf][0][0] + i_ * 4096 + wofs);   \
    }                                                                              \
  } while(0)

  STG(0, 0);                             // prologue: tile 0 (8 issues)

  int cur = 0;
  for (int t = 0; t < 16; ++t){
    asm volatile("s_barrier" ::: "memory");     // all waves done reading buf[cur^1]
    if (t < 15){
      STG(cur ^ 1, (t + 1) << 6);               // stage ALL of t+1 into free buffer
      asm volatile("s_waitcnt vmcnt(8)" ::: "memory");  // tile-t slices certified
    } else {
      asm volatile("s_waitcnt vmcnt(0)" ::: "memory");
    }
    asm volatile("s_barrier" ::: "memory");     // cross-wave certify

    const char* bA = (const char*)&sA[cur][0][0];
    const char* bB = (const char*)&sB[cur][0][0];
    #pragma unroll
    for (int ks = 0; ks < 2; ++ks){
      bf16x8 aq[8], bq[4];
      #pragma unroll
      for (int mi = 0; mi < 8; ++mi){
        const int row = wr * 128 + mi * 16 + fr;
        aq[mi] = *(const bf16x8*)(bA + row * 128 + ((((ks << 2) + fc) ^ fr7) << 4));
      }
      #pragma unroll
      for (int ni = 0; ni < 4; ++ni){
        const int row = wc * 64 + ni * 16 + fr;
        bq[ni] = *(const bf16x8*)(bB + row * 128 + ((((ks << 2) + fc) ^ fr7) << 4));
      }
      __builtin_amdgcn_s_setprio(1);
      #pragma unroll
      for (int mi = 0; mi < 8; ++mi)
        #pragma unroll
        for (int ni = 0; ni < 4; ++ni)
          acc[mi][ni] = __builtin_amdgcn_mfma_f32_16x16x32_bf16(aq[mi], bq[ni], acc[mi][ni], 0, 0, 0);
      __builtin_amdgcn_s_setprio(0);
    }
    cur ^= 1;
  }
  #undef STG

  const int rb0 = m0 + wr * 128 + fc * 4;
  const int cb0 = n0 + wc * 64 + fr;
  #pragma unroll
  for (int mi = 0; mi < 8; ++mi){
    #pragma unroll
    for (int ni = 0; ni < 4; ++ni){
      #pragma unroll
      for (int rg = 0; rg < 4; ++rg){
        C[(long)(rb0 + mi * 16 + rg) * VV + cb0 + ni * 16] = acc[mi][ni][rg];
      }
    }
  }

  // fused LSE partials: per row, this WAVE's 64 cols; 16-lane (fr) shfl reduce
  #pragma unroll
  for (int mi = 0; mi < 8; ++mi){
    #pragma unroll
    for (int rg = 0; rg < 4; ++rg){
      float m4 = fmaxf(fmaxf(acc[mi][0][rg], acc[mi][1][rg]),
                       fmaxf(acc[mi][2][rg], acc[mi][3][rg]));
      #pragma unroll
      for (int o = 1; o < 16; o <<= 1) m4 = fmaxf(m4, __shfl_xor(m4, o, 64));
      float s4 = __expf(acc[mi][0][rg] - m4) + __expf(acc[mi][1][rg] - m4)
               + __expf(acc[mi][2][rg] - m4) + __expf(acc[mi][3][rg] - m4);
      #pragma unroll
      for (int o = 1; o < 16; o <<= 1) s4 += __shfl_xor(s4, o, 64);
      if (fr == 0){
        long pidx = ((long)(rb0 + mi * 16 + rg) << 9) + nt * 4 + wc;  // per-wave slot
        pmax[pidx] = m4;
        psum[pidx] = s4;
      }
    }
  }
}

// ---------------- elementwise / reduction kernels ------------------------------------
__global__ void energy_kernel(const float* __restrict__ ev, float* __restrict__ energy){
  int row = blockIdx.x, t = threadIdx.x;
  long base = (long)row * DD + t * 4;
  float4 v = *(const float4*)(ev + base);
  __shared__ float scratch[4];
  float n2 = block_sum256(v.x*v.x + v.y*v.y + v.z*v.z + v.w*v.w, scratch);
  if (t == 0) energy[row] = sqrtf(n2);
}

__global__ void mean_energy_kernel(const float* __restrict__ energy, float* __restrict__ thr){
  int b = blockIdx.x, t = threadIdx.x;
  float s = 0.f;
  for (int j = t; j < SS; j += 256) s += energy[b * SS + j];
  __shared__ float scratch[4];
  float tot = block_sum256(s, scratch);
  if (t == 0) thr[b] = tot * (1.0f / SS);
}

__global__ void tunnel_kernel(const float* __restrict__ ev, const float* __restrict__ energy,
                              const float* __restrict__ thr,
                              unsigned short* __restrict__ hi, unsigned short* __restrict__ lo){
  int row = blockIdx.x, t = threadIdx.x;
  float scale = (energy[row] < thr[row >> 11]) ? TUNNEL_SCALE : 1.0f;
  long base = (long)row * DD + t * 4;
  float4 v = *(const float4*)(ev + base);
  v.x *= scale; v.y *= scale; v.z *= scale; v.w *= scale;
  ushort4 hv, lv;
  hv.x = f2bf(v.x); lv.x = f2bf(v.x - bf2f(hv.x));
  hv.y = f2bf(v.y); lv.y = f2bf(v.y - bf2f(hv.y));
  hv.z = f2bf(v.z); lv.z = f2bf(v.z - bf2f(hv.z));
  hv.w = f2bf(v.w); lv.w = f2bf(v.w - bf2f(hv.w));
  *(ushort4*)(hi + base) = hv; *(ushort4*)(lo + base) = lv;
}

__global__ void ln_kernel(const float* __restrict__ h, const float* __restrict__ w,
                          const float* __restrict__ b, float* __restrict__ s_f32,
                          unsigned short* __restrict__ hi, unsigned short* __restrict__ lo){
  int row = blockIdx.x, t = threadIdx.x;
  long base = (long)row * DD + t * 4;
  float4 xv = *(const float4*)(h + base);
  __shared__ float scratch[4];
  float sum = block_sum256(xv.x + xv.y + xv.z + xv.w, scratch);
  float ssq = block_sum256(xv.x*xv.x + xv.y*xv.y + xv.z*xv.z + xv.w*xv.w, scratch);
  float mu = sum * (1.0f / DD);
  float var = ssq * (1.0f / DD) - mu * mu;
  float rstd = rsqrtf(var + 1e-5f);
  float4 wv = *(const float4*)(w + t * 4), bv = *(const float4*)(b + t * 4);
  float y0 = (xv.x - mu) * rstd * wv.x + bv.x;
  float y1 = (xv.y - mu) * rstd * wv.y + bv.y;
  float y2 = (xv.z - mu) * rstd * wv.z + bv.z;
  float y3 = (xv.w - mu) * rstd * wv.w + bv.w;
  float4 o; o.x = y0; o.y = y1; o.z = y2; o.w = y3;
  *(float4*)(s_f32 + base) = o;
  ushort4 hv, lv;
  hv.x = f2bf(y0); lv.x = f2bf(y0 - bf2f(hv.x));
  hv.y = f2bf(y1); lv.y = f2bf(y1 - bf2f(hv.y));
  hv.z = f2bf(y2); lv.z = f2bf(y2 - bf2f(hv.z));
  hv.w = f2bf(y3); lv.w = f2bf(y3 - bf2f(hv.w));
  *(ushort4*)(hi + base) = hv; *(ushort4*)(lo + base) = lv;
}

// final LN + unit-normalize -> bf16 (plain; un-amplified error)
__global__ void fln_kernel(const float* __restrict__ s, const float* __restrict__ w,
                           const float* __restrict__ b, unsigned short* __restrict__ uhi){
  int row = blockIdx.x, t = threadIdx.x;
  long base = (long)row * DD + t * 4;
  float4 xv = *(const float4*)(s + base);
  __shared__ float scratch[4];
  float sum = block_sum256(xv.x + xv.y + xv.z + xv.w, scratch);
  float ssq = block_sum256(xv.x*xv.x + xv.y*xv.y + xv.z*xv.z + xv.w*xv.w, scratch);
  float mu = sum * (1.0f / DD);
  float var = ssq * (1.0f / DD) - mu * mu;
  float rstd = rsqrtf(var + 1e-5f);
  float4 wv = *(const float4*)(w + t * 4), bv = *(const float4*)(b + t * 4);
  float y0 = (xv.x - mu) * rstd * wv.x + bv.x;
  float y1 = (xv.y - mu) * rstd * wv.y + bv.y;
  float y2 = (xv.z - mu) * rstd * wv.z + bv.z;
  float y3 = (xv.w - mu) * rstd * wv.w + bv.w;
  float n2 = block_sum256(y0*y0 + y1*y1 + y2*y2 + y3*y3, scratch);
  float inv = 1.0f / (sqrtf(n2) + 1e-12f);
  ushort4 o;
  o.x = f2bf(y0 * inv); o.y = f2bf(y1 * inv);
  o.z = f2bf(y2 * inv); o.w = f2bf(y3 * inv);
  *(ushort4*)(uhi + base) = o;
}

// ---------------- loss: combine per-wave LSE partials (500 per row) ------------------
__global__ void lse_reduce_kernel(const float* __restrict__ pmax, const float* __restrict__ psum,
                                  const float* __restrict__ logits, const int* __restrict__ labels,
                                  float* __restrict__ lrow){
  int idx = blockIdx.x;               // 0..4093
  int b = idx / (SS - 1), qq = idx - b * (SS - 1);
  int row = b * SS + qq;
  int t = threadIdx.x;                // 64 threads
  float m = -1e30f, l = 0.f;
  for (int p = t; p < 500; p += 64){
    float pm = pmax[((long)row << 9) + p], pl = psum[((long)row << 9) + p];
    float M = fmaxf(m, pm);
    l = l * __expf(m - M) + pl * __expf(pm - M);
    m = M;
  }
  #pragma unroll
  for (int o = 1; o < 64; o <<= 1){
    float m2 = __shfl_xor(m, o, 64), l2 = __shfl_xor(l, o, 64);
    float M = fmaxf(m, m2);
    l = l * __expf(m - M) + l2 * __expf(m2 - M);
    m = M;
  }
  if (t == 0){
    float lse = m + __logf(l);
    float tl = logits[(long)row * VV + labels[row + 1]];
    lrow[idx] = lse - tl;
  }
}

__global__ void loss_reduce_kernel(const float* __restrict__ lrow, float* __restrict__ dst){
  __shared__ float scratch[4];
  float s = 0.f;
  for (int j = threadIdx.x; j < BB * (SS - 1); j += 256) s += lrow[j];
  float tot = block_sum256(s, scratch);
  if (threadIdx.x == 0) dst[0] = tot / (float)(BB * (SS - 1));
}

// ---------------- launch ------------------------------------------------------------
extern "C" void kernel_launch(void* const* d_in, const int* in_sizes, int n_in,
                              void* d_out, int out_size, void* d_ws, size_t ws_size,
                              hipStream_t stream) {
  const int*   ids    = (const int*)d_in[0];
  const int*   labels = (const int*)d_in[1];
  const float* proj_w = (const float*)d_in[2];
  const float* proj_b = (const float*)d_in[3];
  const float* ln_w   = (const float*)d_in[4];
  const float* ln_b   = (const float*)d_in[5];
  const float* fln_w  = (const float*)d_in[6];
  const float* fln_b  = (const float*)d_in[7];
  const float* out_w  = (const float*)d_in[8];
  float* out = (float*)d_out;

  char* ws = (char*)d_ws;
  float*          s_f32 = (float*)(ws + 0);                    // 16.78 MB
  unsigned short* op_hi = (unsigned short*)(ws + 16777216);    //  8.39 MB (states/mid/ev/u hi)
  unsigned short* op_lo = (unsigned short*)(ws + 25165824);    //  8.39 MB
  unsigned short* T_hi  = (unsigned short*)(ws + 33554432);    //  8.39 MB (transposed operand)
  unsigned short* T_lo  = (unsigned short*)(ws + 41943040);    //  8.39 MB
  float*          k1    = (float*)(ws + 50331648);             // 16.78 MB (also h pre-LN)
  float*          k2    = (float*)(ws + 67108864);             // 16.78 MB (ev)
  unsigned short* sc_hi = (unsigned short*)(ws + 83886080);    //  8.39 MB (score hi)
  unsigned short* sc_lo = (unsigned short*)(ws + 92274688);    //  8.39 MB
  unsigned short* WhiT  = (unsigned short*)(ws + 100663296);   // 16.78 MB [L][n][k]
  unsigned short* WloT  = (unsigned short*)(ws + 117440512);   // 16.78 MB
  float*          energy= (float*)(ws + 134217728);
  float*          thr   = (float*)(ws + 134234112);
  float*          lrow  = (float*)(ws + 134234368);
  unsigned short* owT   = T_hi;  // 65.54 MB, overlays T/k/score zone (dead at vocab time)
  float*          pmax  = (float*)(ws + 0);          // overlays s_f32 (dead after fln), 8 MB
  float*          psum  = (float*)(ws + 8388608);    // 8 MB

  // proj_w [L][k][n] -> WhiT/WloT [L][n][k] (fp32-split bf16)
  transpose_f32_bf16_kernel<true><<<dim3(16, 16, 8), 256, 0, stream>>>(proj_w, WhiT, WloT, DD, DD);
  // encode
  encode_kernel<<<NROWS, 256, 0, stream>>>(ids, s_f32, op_hi, op_lo);
  transpose_bf16_pair_kernel<<<dim3(16, 32, 4), 256, 0, stream>>>(op_hi, op_lo, T_hi, T_lo, SS, DD);

  for (int l = 0; l < LL; ++l){
    // score1 = tril(states @ statesT)/32  -> bf16 hi/lo
    gemm_nt_kernel<2, 1><<<dim3(256, 2), 512, 0, stream>>>(
        op_hi, op_lo, op_hi, op_lo, nullptr, sc_hi, sc_lo, nullptr, nullptr, nullptr,
        DD, DD, DD, SS, 16, 16, (long)SS * DD, (long)SS * DD, (long)SS * SS, 0.03125f);
    // k1 = score1 @ states ; fused: mid = states + dt*k1 -> op hi/lo
    gemm_nt_kernel<3, 2><<<dim3(128, 2), 512, 0, stream>>>(
        sc_hi, sc_lo, T_hi, T_lo, k1, op_hi, op_lo, nullptr, s_f32, nullptr,
        SS, SS, SS, DD, 16, 8, (long)SS * SS, (long)DD * SS, (long)SS * DD, 1.0f);
    transpose_bf16_pair_kernel<<<dim3(16, 32, 4), 256, 0, stream>>>(op_hi, op_lo, T_hi, T_lo, SS, DD);
    // score2 = tril(mid @ midT)/32
    gemm_nt_kernel<2, 1><<<dim3(256, 2), 512, 0, stream>>>(
        op_hi, op_lo, op_hi, op_lo, nullptr, sc_hi, sc_lo, nullptr, nullptr, nullptr,
        DD, DD, DD, SS, 16, 16, (long)SS * DD, (long)SS * DD, (long)SS * SS, 0.03125f);
    // k2 = score2 @ mid ; fused: ev = states + 0.5dt*(k1+k2)  (written to k2 buffer)
    gemm_nt_kernel<4, 2><<<dim3(128, 2), 512, 0, stream>>>(
        sc_hi, sc_lo, T_hi, T_lo, k2, nullptr, nullptr, nullptr, s_f32, k1,
        SS, SS, SS, DD, 16, 8, (long)SS * SS, (long)DD * SS, (long)SS * DD, 1.0f);
    // row energies + threshold + tunneling
    energy_kernel<<<NROWS, 256, 0, stream>>>(k2, energy);
    mean_energy_kernel<<<BB, 256, 0, stream>>>(energy, thr);
    tunnel_kernel<<<NROWS, 256, 0, stream>>>(k2, energy, thr, op_hi, op_lo);
    // h = ev @ proj_w[l] + proj_b[l]  (into k1)
    gemm_nt_kernel<0, 0><<<dim3(256, 1), 512, 0, stream>>>(
        op_hi, op_lo, WhiT + (long)l * DD * DD, WloT + (long)l * DD * DD,
        k1, nullptr, nullptr, proj_b + l * DD, nullptr, nullptr,
        DD, DD, DD, DD, 32, 8, 0, 0, 0, 1.0f);
    // states = LN(h)
    ln_kernel<<<NROWS, 256, 0, stream>>>(k1, ln_w + l * DD, ln_b + l * DD, s_f32, op_hi, op_lo);
    if (l < LL - 1){
      transpose_bf16_pair_kernel<<<dim3(16, 32, 4), 256, 0, stream>>>(op_hi, op_lo, T_hi, T_lo, SS, DD);
    }
  }

  // out_w [k][v] -> owT [v][k] bf16 (plain); u = unit(LN(states)) -> op_hi
  transpose_f32_bf16_kernel<false><<<dim3(500, 16, 1), 256, 0, stream>>>(out_w, owT, nullptr, DD, VV);
  fln_kernel<<<NROWS, 256, 0, stream>>>(s_f32, fln_w, fln_b, op_hi);
  // logits = u @ out_w  (v3 256^2) + fused per-wave LSE partials
  gemm256_kernel<<<2000, 512, 0, stream>>>(op_hi, owT, out, pmax, psum);
  // loss from partials
  lse_reduce_kernel<<<BB * (SS - 1), 64, 0, stream>>>(pmax, psum, out, labels, lrow);
  loss_reduce_kernel<<<1, 256, 0, stream>>>(lrow, out + (long)NROWS * VV);
}